// Round 1
// baseline (169.124 us; speedup 1.0000x reference)
//
#include <hip/hip_runtime.h>

#define NQ 22
#define DIMN (1u << NQ)

// ---------------- compile-time circuit algebra (circuit is fixed) ----------------
struct MaskSet {
    unsigned L[NQ];      // CNOT-ring layer over GF(2): bit b of Lx = parity(x & L[b])
    unsigned Linv[NQ];
    unsigned xm[NQ];     // conjugated X masks
    unsigned zm[NQ];     // conjugated Z masks (suffix masks)
    unsigned frowHi[5];  // P-toggle masks for y bits 17..21 (columns of Linv)
};

constexpr MaskSet buildMasks() {
    MaskSet M{};
    for (int b = 0; b < NQ; ++b) M.L[b] = 1u << b;
    for (int q = 0; q < NQ; ++q) {
        int bc = NQ - 1 - q, bt = NQ - 1 - ((q + 1) % NQ);
        M.L[bt] ^= M.L[bc];
    }
    unsigned mat[NQ] = {}, aug[NQ] = {};
    for (int b = 0; b < NQ; ++b) { mat[b] = M.L[b]; aug[b] = 1u << b; }
    for (int col = 0; col < NQ; ++col) {
        int piv = col;
        while (!((mat[piv] >> col) & 1u)) ++piv;
        unsigned tm = mat[piv]; mat[piv] = mat[col]; mat[col] = tm;
        unsigned ta = aug[piv]; aug[piv] = aug[col]; aug[col] = ta;
        for (int r = 0; r < NQ; ++r)
            if (r != col && ((mat[r] >> col) & 1u)) { mat[r] ^= mat[col]; aug[r] ^= aug[col]; }
    }
    for (int b = 0; b < NQ; ++b) M.Linv[b] = aug[b];
    for (int j = 0; j < NQ; ++j) {
        int b = NQ - 1 - j;
        unsigned xmv = 0;
        for (int r = 0; r < NQ; ++r)
            if ((aug[r] >> b) & 1u) xmv |= 1u << r;
        M.xm[j] = xmv;       // q0..9: {21-j,20-j}; q10..20: low pairs; q21: {0,20,21}
        M.zm[j] = M.L[b];    // suffix masks
    }
    for (int j = 0; j < 5; ++j) {
        unsigned f = 0;
        for (int r = 0; r < NQ; ++r)
            if ((aug[r] >> (17 + j)) & 1u) f |= 1u << r;
        M.frowHi[j] = f;
    }
    return M;
}
constexpr int topbit_c(unsigned v) { int b = 0; while (v >> (b + 1)) ++b; return b; }
constexpr unsigned unionHi() {
    MaskSet M = buildMasks();
    unsigned u = 0;
    for (int j = 0; j < 5; ++j) u |= M.frowHi[j];
    return u;
}
static_assert((unionHi() & 0xFFFFu) == 0, "frowHi must only touch bits 16..21");

// ---- orbit structure for the fused slice-measurement kernel (q0,q4,q9,q21) ----
// f4-space generators from the three distinct high-bit X-pair masks.
constexpr unsigned orbGen(int which) {
    MaskSet M = buildMasks();
    return (which == 0 ? M.xm[0] : which == 1 ? M.xm[4] : M.xm[9]) >> 2;
}
constexpr int orbS21() {   // q21's f4-mask as a XOR-combo of the generators
    MaskSet M = buildMasks();
    unsigned GA = M.xm[0] >> 2, GB = M.xm[4] >> 2, GC = M.xm[9] >> 2;
    unsigned GQ = M.xm[21] >> 2;
    for (int s = 1; s < 8; ++s) {
        unsigned c = ((s & 1) ? GA : 0u) ^ ((s & 2) ? GB : 0u) ^ ((s & 4) ? GC : 0u);
        if (c == GQ) return s;
    }
    return -1;
}
constexpr bool orbitOK() {
    unsigned GA = orbGen(0), GB = orbGen(1), GC = orbGen(2);
    int cA = topbit_c(GA), cB = topbit_c(GB), cC = topbit_c(GC);
    if (!(cC < cB && cB < cA) || cA > 19) return false;
    if (((GA >> cB) & 1u) || ((GA >> cC) & 1u)) return false;
    if (((GB >> cA) & 1u) || ((GB >> cC) & 1u)) return false;
    if (((GC >> cA) & 1u) || ((GC >> cB) & 1u)) return false;
    return orbS21() > 0;
}
static_assert(orbitOK(), "orbit structure for fused slice measurement must hold");

__device__ __forceinline__ float wave_sum(float v) {
    v += __shfl_down(v, 32); v += __shfl_down(v, 16); v += __shfl_down(v, 8);
    v += __shfl_down(v, 4);  v += __shfl_down(v, 2);  v += __shfl_down(v, 1);
    return v;
}
__device__ __forceinline__ float fflip(float v, unsigned sbit31) {
    return __int_as_float(__float_as_int(v) ^ (int)sbit31);
}
__device__ __forceinline__ unsigned ph4(unsigned g) { return g ^ ((g >> 6) & 3u); }

// ---------------- prep: zero accumulators, compute cos/sin tables ----------------
__global__ __launch_bounds__(256) void k_prep(const float* __restrict__ theta,
                                              float* __restrict__ acc,
                                              float* __restrict__ trig) {
    int t = threadIdx.x;
    acc[t] = 0.f;
    if (t < 2 * NQ) {
        int l = t / NQ, q = t % NQ, b = NQ - 1 - q;
        float h = 0.5f * theta[t];
        trig[l * 2 * NQ + b]      = cosf(h);
        trig[l * 2 * NQ + NQ + b] = sinf(h);
    }
}

// ---- generator in e=bits17..21 tile + gates 17..21 + measure q1,q2,q3 ----
__global__ __launch_bounds__(256, 1) void k_genHi(float* __restrict__ phi,
                                                  const float* __restrict__ trig,
                                                  float* __restrict__ acc) {
    constexpr MaskSet M = buildMasks();
    __shared__ float red[4 * 12];
    unsigned base = blockIdx.x * 256u + threadIdx.x;       // y bits 0..16
    unsigned P0 = 0;
#pragma unroll
    for (int b = 0; b < NQ; ++b)
        P0 |= ((unsigned)__popc(base & M.Linv[b]) & 1u) << b;
    // common product over bits 1..15 (consumed immediately, not kept)
    float pc = 1.f;
#pragma unroll
    for (int b = 1; b < 16; ++b) {
        float cvb = trig[b], svb = trig[NQ + b];
        pc *= ((P0 >> b) & 1u) ? svb : cvb;
    }
    float cv0 = trig[0], sv0 = trig[NQ];
    float C0 = pc * ((P0 & 1u) ? sv0 : cv0);
    float C1 = pc * ((P0 & 1u) ? cv0 : -sv0);
    // variable part: bits 16..21
    float cb[6], sb[6];
#pragma unroll
    for (int k = 0; k < 6; ++k) { cb[k] = trig[16 + k]; sb[k] = trig[NQ + 16 + k]; }
    unsigned u0 = P0 >> 16;                                // 6 bits
    float v0[32], v1[32];
#pragma unroll
    for (int e = 0; e < 32; ++e) {
        unsigned F = 0;
        if (e & 1)  F ^= M.frowHi[0];
        if (e & 2)  F ^= M.frowHi[1];
        if (e & 4)  F ^= M.frowHi[2];
        if (e & 8)  F ^= M.frowHi[3];
        if (e & 16) F ^= M.frowHi[4];
        unsigned u = u0 ^ (F >> 16);
        float vp = (u & 1u) ? sb[0] : cb[0];
#pragma unroll
        for (int k = 1; k < 6; ++k) vp *= ((u >> k) & 1u) ? sb[k] : cb[k];
        v0[e] = vp * C0;
        v1[e] = vp * C1;
    }
    float c2[5], s2[5];
#pragma unroll
    for (int j = 0; j < 5; ++j) {
        c2[j] = trig[2 * NQ + 17 + j];
        s2[j] = trig[3 * NQ + 17 + j];
    }
#pragma unroll
    for (int j = 0; j < 5; ++j) {
#pragma unroll
        for (int e = 0; e < 32; ++e) {
            if (!(e & (1 << j))) {
                int e1 = e | (1 << j);
                float a0 = v0[e], a1 = v0[e1];
                v0[e]  = c2[j] * a0 - s2[j] * a1;
                v0[e1] = s2[j] * a0 + c2[j] * a1;
                float b0 = v1[e], b1 = v1[e1];
                v1[e]  = c2[j] * b0 - s2[j] * b1;
                v1[e1] = s2[j] * b0 + c2[j] * b1;
            }
        }
    }
#pragma unroll
    for (int e = 0; e < 32; ++e) {
        unsigned a = base | ((unsigned)e << 17);
        phi[a] = v0[e];
        phi[DIMN + a] = v1[e];
    }
    // measure q1..q3 (x-pairs and z-masks entirely within bits 17..21)
    int lane = threadIdx.x & 63, w = threadIdx.x >> 6;
#pragma unroll
    for (int i = 1; i <= 3; ++i) {
        unsigned ex  = M.xm[i] >> 17;
        unsigned zme = M.zm[i] >> 17;
        float t00 = 0.f, t11 = 0.f, t01 = 0.f, u01 = 0.f;
#pragma unroll
        for (int e = 0; e < 32; ++e) {
            int ep = e ^ (int)ex;
            t00 += v0[e] * v0[ep];
            t11 += v1[e] * v1[ep];
            float p = v0[e] * v1[ep];
            t01 += p;
            unsigned sg = ((unsigned)__popc((unsigned)ep & zme) & 1u) << 31;
            u01 += fflip(p, sg);
        }
        float vals[4] = { t00, t11, t01, u01 };
#pragma unroll
        for (int j = 0; j < 4; ++j) {
            float v = wave_sum(vals[j]);
            if (lane == 0) red[w * 12 + (i - 1) * 4 + j] = v;
        }
    }
    __syncthreads();
    int t = threadIdx.x;
    if (t < 12) {
        float r = red[t] + red[12 + t] + red[24 + t] + red[36 + t];
        atomicAdd(&acc[4 + t], r);                          // acc[4..15] = q1..q3
    }
}

// ---- e=bits12..16 tile: gates 12..16 + measure q5..q8 (32-elem tile, 8 waves/CU) ----
__global__ __launch_bounds__(256, 1) void k_midA(float* __restrict__ phi,
                                                 const float* __restrict__ trig,
                                                 float* __restrict__ acc) {
    constexpr MaskSet M = buildMasks();
    __shared__ float red[4 * 16];
    unsigned tid = blockIdx.x * 256u + threadIdx.x;        // [0, 2^17)
    unsigned base = (tid & 0xFFFu) | ((tid >> 12) << 17);  // bits 0..11 + 17..21
    float v0[32], v1[32];
#pragma unroll
    for (int e = 0; e < 32; ++e) {
        unsigned a = base | ((unsigned)e << 12);
        v0[e] = phi[a];
        v1[e] = phi[DIMN + a];
    }
    float c[5], s[5];
#pragma unroll
    for (int j = 0; j < 5; ++j) {
        c[j] = trig[2 * NQ + 12 + j];
        s[j] = trig[3 * NQ + 12 + j];
    }
#pragma unroll
    for (int j = 0; j < 5; ++j) {
#pragma unroll
        for (int e = 0; e < 32; ++e) {
            if (!(e & (1 << j))) {
                int e1 = e | (1 << j);
                float a0 = v0[e], a1 = v0[e1];
                v0[e]  = c[j] * a0 - s[j] * a1;
                v0[e1] = s[j] * a0 + c[j] * a1;
                float b0 = v1[e], b1 = v1[e1];
                v1[e]  = c[j] * b0 - s[j] * b1;
                v1[e1] = s[j] * b0 + c[j] * b1;
            }
        }
    }
#pragma unroll
    for (int e = 0; e < 32; ++e) {
        unsigned a = base | ((unsigned)e << 12);
        phi[a] = v0[e];
        phi[DIMN + a] = v1[e];
    }
    // measure q5..q8 (x-pairs within bits 12..16; z-masks suffix >= 13)
    int lane = threadIdx.x & 63, w = threadIdx.x >> 6;
#pragma unroll
    for (int i = 5; i <= 8; ++i) {
        unsigned ex  = (M.xm[i] >> 12) & 31u;
        unsigned zme = (M.zm[i] >> 12) & 31u;
        unsigned bs31 = ((unsigned)__popc(base & M.zm[i]) & 1u) << 31;
        float t00 = 0.f, t11 = 0.f, t01 = 0.f, u01 = 0.f;
#pragma unroll
        for (int e = 0; e < 32; ++e) {
            int ep = e ^ (int)ex;
            t00 += v0[e] * v0[ep];
            t11 += v1[e] * v1[ep];
            float p = v0[e] * v1[ep];
            t01 += p;
            unsigned sg = ((unsigned)__popc((unsigned)ep & zme) & 1u) << 31;
            u01 += fflip(p, sg ^ bs31);
        }
        float vals[4] = { t00, t11, t01, u01 };
#pragma unroll
        for (int j = 0; j < 4; ++j) {
            float v = wave_sum(vals[j]);
            if (lane == 0) red[w * 16 + (i - 5) * 4 + j] = v;
        }
    }
    __syncthreads();
    int t = threadIdx.x;
    if (t < 16) {
        float r = red[t] + red[16 + t] + red[32 + t] + red[48 + t];
        atomicAdd(&acc[20 + t], r);                         // acc[20..35] = q5..q8
    }
}

// ---- RY layer 2 bits 0..11 + q10..q20 X/Y + ALL Z measurements ----
__global__ __launch_bounds__(256) void k_low(float* __restrict__ phi,
                                             const float* __restrict__ trig,
                                             float* __restrict__ acc) {
    constexpr MaskSet M = buildMasks();
    __shared__ float As[4096];
    __shared__ float Bs[4096];
    __shared__ float red[4 * 44];
    float4* As4 = (float4*)As;
    float4* Bs4 = (float4*)Bs;
    int t = threadIdx.x;
    unsigned base = blockIdx.x * 4096u;
    float a[16], b[16];

    // ---- phase 0: global load (16 consecutive elems/thread), gates bits 0..3 ----
    {
        const float4* g0 = (const float4*)(phi + base);
        const float4* g1 = (const float4*)(phi + DIMN + base);
#pragma unroll
        for (int k = 0; k < 4; ++k) {
            float4 va = g0[4 * t + k];
            a[4 * k] = va.x; a[4 * k + 1] = va.y; a[4 * k + 2] = va.z; a[4 * k + 3] = va.w;
            float4 vb = g1[4 * t + k];
            b[4 * k] = vb.x; b[4 * k + 1] = vb.y; b[4 * k + 2] = vb.z; b[4 * k + 3] = vb.w;
        }
#pragma unroll
        for (int g = 0; g < 4; ++g) {
            float c = trig[2 * NQ + g], s = trig[3 * NQ + g];
#pragma unroll
            for (int e = 0; e < 16; ++e) {
                if (!(e & (1 << g))) {
                    int e1 = e | (1 << g);
                    float x0 = a[e], x1 = a[e1];
                    a[e] = c * x0 - s * x1; a[e1] = s * x0 + c * x1;
                    float y0 = b[e], y1 = b[e1];
                    b[e] = c * y0 - s * y1; b[e1] = s * y0 + c * y1;
                }
            }
        }
        unsigned sw = (unsigned)(t >> 4) & 3u;
#pragma unroll
        for (int k = 0; k < 4; ++k) {
            unsigned f = ((unsigned)(4 * t + k)) ^ sw;
            As4[f] = make_float4(a[4 * k], a[4 * k + 1], a[4 * k + 2], a[4 * k + 3]);
            Bs4[f] = make_float4(b[4 * k], b[4 * k + 1], b[4 * k + 2], b[4 * k + 3]);
        }
    }
    __syncthreads();

    // ---- phase 1: exchange to bits 4..7 ownership, gates bits 4..7 ----
    {
        unsigned lo = (unsigned)t & 15u, hi = (unsigned)t >> 4;
        unsigned swz = (hi & 3u) << 2;
#pragma unroll
        for (int j = 0; j < 16; ++j) {
            unsigned i = lo | ((unsigned)j << 4) | (hi << 8);
            a[j] = As[i ^ swz];
            b[j] = Bs[i ^ swz];
        }
#pragma unroll
        for (int g = 0; g < 4; ++g) {
            float c = trig[2 * NQ + 4 + g], s = trig[3 * NQ + 4 + g];
#pragma unroll
            for (int e = 0; e < 16; ++e) {
                if (!(e & (1 << g))) {
                    int e1 = e | (1 << g);
                    float x0 = a[e], x1 = a[e1];
                    a[e] = c * x0 - s * x1; a[e1] = s * x0 + c * x1;
                    float y0 = b[e], y1 = b[e1];
                    b[e] = c * y0 - s * y1; b[e1] = s * y0 + c * y1;
                }
            }
        }
#pragma unroll
        for (int j = 0; j < 16; ++j) {
            unsigned i = lo | ((unsigned)j << 4) | (hi << 8);
            As[i ^ swz] = a[j];
            Bs[i ^ swz] = b[j];
        }
    }
    __syncthreads();

    // ---- phase 2: exchange to bits 8..11 ownership, gates bits 8..11, write out ----
    {
#pragma unroll
        for (int j = 0; j < 16; ++j) {
            unsigned i = (unsigned)t | ((unsigned)j << 8);
            unsigned p = i ^ (((unsigned)j & 3u) << 2);
            a[j] = As[p];
            b[j] = Bs[p];
        }
#pragma unroll
        for (int g = 0; g < 4; ++g) {
            float c = trig[2 * NQ + 8 + g], s = trig[3 * NQ + 8 + g];
#pragma unroll
            for (int e = 0; e < 16; ++e) {
                if (!(e & (1 << g))) {
                    int e1 = e | (1 << g);
                    float x0 = a[e], x1 = a[e1];
                    a[e] = c * x0 - s * x1; a[e1] = s * x0 + c * x1;
                    float y0 = b[e], y1 = b[e1];
                    b[e] = c * y0 - s * y1; b[e1] = s * y0 + c * y1;
                }
            }
        }
#pragma unroll
        for (int j = 0; j < 16; ++j) {
            unsigned i = (unsigned)t | ((unsigned)j << 8);
            phi[base + i] = a[j];
            phi[DIMN + base + i] = b[j];
            unsigned p = i ^ (((unsigned)j & 3u) << 2);
            As[p] = a[j];
            Bs[p] = b[j];
        }
    }

    // ---- fused Z measurement from final registers a[],b[] ----
    float SSv[3], z0v[3], z1v[3], z2v[3], d4v[3];
    {
#pragma unroll
        for (int c = 0; c < 3; ++c) {
            float p[16];
#pragma unroll
            for (int j = 0; j < 16; ++j)
                p[j] = (c == 0) ? a[j] * a[j] : (c == 1) ? b[j] * b[j] : a[j] * b[j];
            float s1[8], d1[8];
#pragma unroll
            for (int j = 0; j < 8; ++j) { s1[j] = p[j] + p[j + 8]; d1[j] = p[j] - p[j + 8]; }
            float s2[4], d2[4];
#pragma unroll
            for (int j = 0; j < 4; ++j) { s2[j] = s1[j] + s1[j + 4]; d2[j] = d1[j] - d1[j + 4]; }
            float d3a = d2[0] - d2[2], d3b = d2[1] - d2[3];
            SSv[c] = (s2[0] + s2[1]) + (s2[2] + s2[3]);
            z0v[c] = ((d1[0] + d1[1]) + (d1[2] + d1[3])) + ((d1[4] + d1[5]) + (d1[6] + d1[7]));
            z1v[c] = (d2[0] + d2[1]) + (d2[2] + d2[3]);
            z2v[c] = d3a + d3b;
            d4v[c] = d3a - d3b;
        }
    }
    {
        unsigned Wt = (unsigned)t;
        Wt ^= Wt >> 1; Wt ^= Wt >> 2; Wt ^= Wt >> 4;
        int lane = t & 63, w = t >> 6;
#pragma unroll
        for (int c = 0; c < 3; ++c) {
            float v;
            v = wave_sum(SSv[c]); if (lane == 0) red[w * 39 + c] = v;
            v = wave_sum(z0v[c]); if (lane == 0) red[w * 39 + 3 + c] = v;
            v = wave_sum(z1v[c]); if (lane == 0) red[w * 39 + 6 + c] = v;
            v = wave_sum(z2v[c]); if (lane == 0) red[w * 39 + 9 + c] = v;
            v = wave_sum(d4v[c]); if (lane == 0) red[w * 39 + 12 + c] = v;
#pragma unroll
            for (int k = 4; k < 12; ++k) {
                unsigned sb = ((Wt >> (11 - k)) & 1u) << 31;
                v = wave_sum(fflip(d4v[c], sb));
                if (lane == 0) red[w * 39 + 3 + 3 * k + c] = v;
            }
        }
    }
    __syncthreads();
    if (t < 66) {
        int c = t % 3, q = t / 3;
        int slot = (q == 0 || q == 21) ? (3 + 33 + c) : (q < 10 ? c : 3 + 3 * (q - 10) + c);
        float val = red[slot] + red[39 + slot] + red[78 + slot] + red[117 + slot];
        unsigned sg = (unsigned)__popc(base & M.zm[q]) & 1u;
        atomicAdd(&acc[4 * NQ + 3 * q + c], sg ? -val : val);
    }
    __syncthreads();

    int lane = t & 63, w = t >> 6;

    // ---- q10..q12 measured from registers (x-pairs within bits 8..11 = j bits) ----
#pragma unroll
    for (int i = 0; i < 3; ++i) {
        constexpr int qn0 = 10;
        unsigned je  = (M.xm[qn0 + i] >> 8) & 15u;
        unsigned zmj = (M.zm[qn0 + i] >> 8) & 15u;
        unsigned zb31 = ((unsigned)__popc(base & M.zm[qn0 + i]) & 1u) << 31;
        float t00 = 0.f, t11 = 0.f, t01 = 0.f, u01 = 0.f;
#pragma unroll
        for (int j = 0; j < 16; ++j) {
            int jp = j ^ (int)je;
            t00 += a[j] * a[jp];
            t11 += b[j] * b[jp];
            float p = a[j] * b[jp];
            t01 += p;
            unsigned sg = ((unsigned)__popc((unsigned)jp & zmj) & 1u) << 31;
            u01 += fflip(p, sg ^ zb31);
        }
        float vals[4] = { t00, t11, t01, u01 };
#pragma unroll
        for (int j = 0; j < 4; ++j) {
            float v = wave_sum(vals[j]);
            if (lane == 0) red[w * 44 + 4 * i + j] = v;
        }
    }

    // ---- q13..q20 (masks within bits 0..8), vectorized from LDS ----
#pragma unroll
    for (int i = 3; i < 11; ++i) {
        unsigned m = M.xm[10 + i], zm = M.zm[10 + i];
        unsigned zb = (unsigned)__popc(base & zm) & 1u;
        float t00 = 0.f, t11 = 0.f, t01 = 0.f, u01 = 0.f;
        if (i < 10) {
            int gb = topbit_c(M.xm[10 + i]) - 2;
            unsigned mg4 = m >> 2;
            unsigned swap2 = m & 3u;            // 0 or 2
#pragma unroll
            for (int r = 0; r < 2; ++r) {
                unsigned gc = (unsigned)t + 256u * r;
                unsigned g = ((gc >> gb) << (gb + 1)) | (gc & ((1u << gb) - 1u));
                unsigned gx = g ^ mg4;
                float4 a0 = As4[ph4(g)],  a1 = Bs4[ph4(g)];
                float4 b0 = As4[ph4(gx)], b1 = Bs4[ph4(gx)];
                if (swap2) {
                    b0 = make_float4(b0.z, b0.w, b0.x, b0.y);
                    b1 = make_float4(b1.z, b1.w, b1.x, b1.y);
                }
                unsigned szg = ((unsigned)__popc((g << 2) & zm) + zb) & 1u;
                unsigned szx = ((unsigned)__popc((gx << 2) & zm) + zb) & 1u;
                unsigned fg = szg << 31, fx = szx << 31;
                const float* A0 = &a0.x; const float* A1 = &a1.x;
                const float* B0 = &b0.x; const float* B1 = &b1.x;
#pragma unroll
                for (int j = 0; j < 4; ++j) {
                    t00 += A0[j] * B0[j];
                    t11 += A1[j] * B1[j];
                    float p = A0[j] * B1[j], r2 = B0[j] * A1[j];
                    t01 += p + r2;
                    u01 += fflip(p, fx) + fflip(r2, fg);
                }
            }
            t00 *= 2.f; t11 *= 2.f;
        } else {
            // q20: m = 3, partner within float4
#pragma unroll
            for (int k = 0; k < 4; ++k) {
                unsigned g = (unsigned)t + 256u * k;
                float4 a0 = As4[ph4(g)], a1 = Bs4[ph4(g)];
                unsigned szg = ((unsigned)__popc((g << 2) & zm) + zb) & 1u;
                const float* A0 = &a0.x; const float* A1 = &a1.x;
#pragma unroll
                for (int j = 0; j < 4; ++j) {
                    int jx = j ^ 3;
                    float p = A0[j] * A0[jx];
                    float q2 = A1[j] * A1[jx];
                    float cr = A0[j] * A1[jx];
                    t00 += p; t11 += q2; t01 += cr;
                    unsigned sj = ((unsigned)(jx >> 1) & 1u) ^ szg;   // zm&3 == 2
                    u01 += fflip(cr, sj << 31);
                }
            }
        }
        float vals[4] = { t00, t11, t01, u01 };
#pragma unroll
        for (int j = 0; j < 4; ++j) {
            float v = wave_sum(vals[j]);
            if (lane == 0) red[w * 44 + 4 * i + j] = v;
        }
    }
    __syncthreads();
    if (t < 44) {
        float r = red[t] + red[44 + t] + red[88 + t] + red[132 + t];
        atomicAdd(&acc[40 + t], r);
    }
}

// ------- fused single-pass X/Y measurements for q0, q4, q9, q21 --------------
// The three f4-space pair masks A={19,18} (q0), B={15,14} (q4), C={10,9} (q9)
// generate an 8-element orbit; q21 = A with a within-f4 swap. One thread loads
// the 8 orbit partners x 2 logical states (16 float4) and computes all four
// measurements from registers: 32 MB read total instead of 4 x 32 MB passes.
__global__ __launch_bounds__(256) void k_measF(const float* __restrict__ phi,
                                               float* __restrict__ acc) {
    constexpr MaskSet M = buildMasks();
    constexpr unsigned GA = orbGen(0), GB = orbGen(1), GC = orbGen(2);
    constexpr int pc0 = topbit_c(GC), pc1 = topbit_c(GB), pc2 = topbit_c(GA);
    __shared__ float red[4 * 16];
    unsigned t = blockIdx.x * 256u + threadIdx.x;          // 17-bit orbit id
    unsigned g = t;                                        // insert 0 at canonical bits
    g = ((g >> pc0) << (pc0 + 1)) | (g & ((1u << pc0) - 1u));
    g = ((g >> pc1) << (pc1 + 1)) | (g & ((1u << pc1) - 1u));
    g = ((g >> pc2) << (pc2 + 1)) | (g & ((1u << pc2) - 1u));
    const float4* P0 = (const float4*)phi;
    const float4* P1 = (const float4*)(phi + DIMN);
    unsigned idx[8];
    float4 u4[8], w4[8];
#pragma unroll
    for (int s = 0; s < 8; ++s) {
        idx[s] = g ^ ((s & 1) ? GA : 0u) ^ ((s & 2) ? GB : 0u) ^ ((s & 4) ? GC : 0u);
        u4[s] = P0[idx[s]];
        w4[s] = P1[idx[s]];
    }
    constexpr int QN[4] = { 0, 4, 9, 21 };
    constexpr int SX[4] = { 1, 2, 4, orbS21() };
    float res[16];
#pragma unroll
    for (int qi = 0; qi < 4; ++qi) {
        const unsigned xq = M.xm[QN[qi]];
        const unsigned zq = M.zm[QN[qi]];
        const int sx = SX[qi];
        const int mu = (int)(xq & 3u);                     // within-f4 partner xor
        const unsigned zh = zq >> 2, zl = zq & 3u;
        unsigned fz[8];
#pragma unroll
        for (int s = 0; s < 8; ++s)
            fz[s] = ((unsigned)__popc(idx[s] & zh) & 1u) << 31;
        unsigned pj31[4];
#pragma unroll
        for (int j = 0; j < 4; ++j)
            pj31[j] = ((unsigned)__popc((unsigned)j & zl) & 1u) << 31;
        float t00 = 0.f, t11 = 0.f, t01 = 0.f, u01 = 0.f;
#pragma unroll
        for (int s = 0; s < 8; ++s) {
            const int s2 = s ^ sx;
            const float* A0 = &u4[s].x;
            const float* A1 = &w4[s].x;
            const float* B0 = &u4[s2].x;
            const float* B1 = &w4[s2].x;
            const unsigned fe = fz[s2];                    // Z-parity of partner f4
#pragma unroll
            for (int j = 0; j < 4; ++j) {
                const int jp = j ^ mu;
                t00 += A0[j] * B0[jp];
                t11 += A1[j] * B1[jp];
                float p = A0[j] * B1[jp];
                t01 += p;
                u01 += fflip(p, fe ^ pj31[jp]);
            }
        }
        res[4 * qi + 0] = t00; res[4 * qi + 1] = t11;
        res[4 * qi + 2] = t01; res[4 * qi + 3] = u01;
    }
    int lane = threadIdx.x & 63, w = threadIdx.x >> 6;
#pragma unroll
    for (int k = 0; k < 16; ++k) {
        float v = wave_sum(res[k]);
        if (lane == 0) red[w * 16 + k] = v;
    }
    __syncthreads();
    int tt = threadIdx.x;
    if (tt < 16) {
        int qi = tt >> 2;
        int base4 = (qi == 0) ? 0 : (qi == 1) ? 16 : (qi == 2) ? 36 : 84;  // 4*qn
        float r = red[tt] + red[16 + tt] + red[32 + tt] + red[48 + tt];
        atomicAdd(&acc[base4 + (tt & 3)], r);
    }
}

// ---------------- finalize: combine 154 sums into the scalar loss ----------------
__global__ __launch_bounds__(64) void k_final(const float* __restrict__ acc,
                                              float* __restrict__ out) {
    int t = threadIdx.x;
    float v = 0.f;
    if (t < NQ) {
        float t00 = acc[4 * t], t11 = acc[4 * t + 1];
        float t01 = acc[4 * t + 2], u01 = acc[4 * t + 3];
        float d = t00 - t11;
        v = 0.5f * d * d + 2.f * t01 * t01 + 2.f * u01 * u01;   // X op + Y op
    } else if (t < 2 * NQ) {
        int q = t - NQ;
        float z0 = acc[4 * NQ + 3 * q], z1 = acc[4 * NQ + 3 * q + 1];
        float zz = acc[4 * NQ + 3 * q + 2];
        float d = z0 - z1;
        v = 0.5f * d * d + 2.f * zz * zz;                       // Z op
    }
    v += __shfl_down(v, 32); v += __shfl_down(v, 16); v += __shfl_down(v, 8);
    v += __shfl_down(v, 4);  v += __shfl_down(v, 2);  v += __shfl_down(v, 1);
    if (t == 0) out[0] = v;
}

extern "C" void kernel_launch(void* const* d_in, const int* in_sizes, int n_in,
                              void* d_out, int out_size, void* d_ws, size_t ws_size,
                              hipStream_t stream) {
    const float* theta = (const float*)d_in[0];
    float* out  = (float*)d_out;
    float* ws   = (float*)d_ws;
    float* phi  = ws;                          // 2 * DIMN floats (32 MB)
    float* acc  = ws + 2 * (size_t)DIMN;       // 256 floats
    float* trig = acc + 256;                   // 88 floats

    k_prep<<<1, 256, 0, stream>>>(theta, acc, trig);
    k_genHi<<<512, 256, 0, stream>>>(phi, trig, acc);
    k_midA<<<512, 256, 0, stream>>>(phi, trig, acc);
    k_low<<<1024, 256, 0, stream>>>(phi, trig, acc);
    k_measF<<<512, 256, 0, stream>>>(phi, acc);
    k_final<<<1, 64, 0, stream>>>(acc, out);
}

// Round 2
// 157.706 us; speedup vs baseline: 1.0724x; 1.0724x over previous
//
#include <hip/hip_runtime.h>

#define NQ 22
#define DIMN (1u << NQ)

// ---------------- compile-time circuit algebra (circuit is fixed) ----------------
struct MaskSet {
    unsigned L[NQ];      // CNOT-ring layer over GF(2): bit b of Lx = parity(x & L[b])
    unsigned Linv[NQ];
    unsigned xm[NQ];     // conjugated X masks
    unsigned zm[NQ];     // conjugated Z masks (suffix masks)
    unsigned frowHi[5];  // P-toggle masks for y bits 17..21 (columns of Linv)
};

constexpr MaskSet buildMasks() {
    MaskSet M{};
    for (int b = 0; b < NQ; ++b) M.L[b] = 1u << b;
    for (int q = 0; q < NQ; ++q) {
        int bc = NQ - 1 - q, bt = NQ - 1 - ((q + 1) % NQ);
        M.L[bt] ^= M.L[bc];
    }
    unsigned mat[NQ] = {}, aug[NQ] = {};
    for (int b = 0; b < NQ; ++b) { mat[b] = M.L[b]; aug[b] = 1u << b; }
    for (int col = 0; col < NQ; ++col) {
        int piv = col;
        while (!((mat[piv] >> col) & 1u)) ++piv;
        unsigned tm = mat[piv]; mat[piv] = mat[col]; mat[col] = tm;
        unsigned ta = aug[piv]; aug[piv] = aug[col]; aug[col] = ta;
        for (int r = 0; r < NQ; ++r)
            if (r != col && ((mat[r] >> col) & 1u)) { mat[r] ^= mat[col]; aug[r] ^= aug[col]; }
    }
    for (int b = 0; b < NQ; ++b) M.Linv[b] = aug[b];
    for (int j = 0; j < NQ; ++j) {
        int b = NQ - 1 - j;
        unsigned xmv = 0;
        for (int r = 0; r < NQ; ++r)
            if ((aug[r] >> b) & 1u) xmv |= 1u << r;
        M.xm[j] = xmv;       // q0..9: {21-j,20-j}; q10..20: low pairs; q21: {0,20,21}
        M.zm[j] = M.L[b];    // suffix masks
    }
    for (int j = 0; j < 5; ++j) {
        unsigned f = 0;
        for (int r = 0; r < NQ; ++r)
            if ((aug[r] >> (17 + j)) & 1u) f |= 1u << r;
        M.frowHi[j] = f;
    }
    return M;
}
constexpr int topbit_c(unsigned v) { int b = 0; while (v >> (b + 1)) ++b; return b; }
constexpr unsigned unionHi() {
    MaskSet M = buildMasks();
    unsigned u = 0;
    for (int j = 0; j < 5; ++j) u |= M.frowHi[j];
    return u;
}
static_assert((unionHi() & 0xFFFFu) == 0, "frowHi must only touch bits 16..21");

// ---- orbit structure for the fused slice-measurement kernel (q0,q4,q9,q21) ----
constexpr unsigned orbGen(int which) {
    MaskSet M = buildMasks();
    return (which == 0 ? M.xm[0] : which == 1 ? M.xm[4] : M.xm[9]) >> 2;
}
constexpr int orbS21() {
    MaskSet M = buildMasks();
    unsigned GA = M.xm[0] >> 2, GB = M.xm[4] >> 2, GC = M.xm[9] >> 2;
    unsigned GQ = M.xm[21] >> 2;
    for (int s = 1; s < 8; ++s) {
        unsigned c = ((s & 1) ? GA : 0u) ^ ((s & 2) ? GB : 0u) ^ ((s & 4) ? GC : 0u);
        if (c == GQ) return s;
    }
    return -1;
}
constexpr bool orbitOK() {
    unsigned GA = orbGen(0), GB = orbGen(1), GC = orbGen(2);
    int cA = topbit_c(GA), cB = topbit_c(GB), cC = topbit_c(GC);
    if (!(cC < cB && cB < cA) || cA > 19) return false;
    if (((GA >> cB) & 1u) || ((GA >> cC) & 1u)) return false;
    if (((GB >> cA) & 1u) || ((GB >> cC) & 1u)) return false;
    if (((GC >> cA) & 1u) || ((GC >> cB) & 1u)) return false;
    return orbS21() > 0;
}
static_assert(orbitOK(), "orbit structure for fused slice measurement must hold");

__device__ __forceinline__ float fflip(float v, unsigned sbit31) {
    return __int_as_float(__float_as_int(v) ^ (int)sbit31);
}
__device__ __forceinline__ unsigned ph4(unsigned g) { return g ^ ((g >> 6) & 3u); }

// 4-quantity wave reduction: 7 shfl instead of 24.
// Returns: lane L holds the full-wave total of quantity (L&3).
__device__ __forceinline__ float fold4(float a, float b, float c, float d, int lane) {
    bool p0 = (lane & 1) != 0;
    float kL = p0 ? b : a, sL = p0 ? a : b;
    kL += __shfl_xor(sL, 1);
    float kH = p0 ? d : c, sH = p0 ? c : d;
    kH += __shfl_xor(sH, 1);
    bool p1 = (lane & 2) != 0;
    float k2 = p1 ? kH : kL, s2 = p1 ? kL : kH;
    k2 += __shfl_xor(s2, 2);
    k2 += __shfl_xor(k2, 4);
    k2 += __shfl_xor(k2, 8);
    k2 += __shfl_xor(k2, 16);
    k2 += __shfl_xor(k2, 32);
    return k2;
}

// ---------------- prep: zero accumulators, compute cos/sin tables ----------------
__global__ __launch_bounds__(256) void k_prep(const float* __restrict__ theta,
                                              float* __restrict__ acc,
                                              float* __restrict__ trig) {
    int t = threadIdx.x;
    acc[t] = 0.f;
    if (t < 2 * NQ) {
        int l = t / NQ, q = t % NQ, b = NQ - 1 - q;
        float h = 0.5f * theta[t];
        trig[l * 2 * NQ + b]      = cosf(h);
        trig[l * 2 * NQ + NQ + b] = sinf(h);
    }
}

// ---- generator in e=bits17..21 tile + gates 17..21 + measure q1,q2,q3 ----
__global__ __launch_bounds__(256, 1) void k_genHi(float* __restrict__ phi,
                                                  const float* __restrict__ trig,
                                                  float* __restrict__ acc) {
    constexpr MaskSet M = buildMasks();
    __shared__ float red[4 * 12];
    unsigned base = blockIdx.x * 256u + threadIdx.x;       // y bits 0..16
    unsigned P0 = 0;
#pragma unroll
    for (int b = 0; b < NQ; ++b)
        P0 |= ((unsigned)__popc(base & M.Linv[b]) & 1u) << b;
    float pc = 1.f;
#pragma unroll
    for (int b = 1; b < 16; ++b) {
        float cvb = trig[b], svb = trig[NQ + b];
        pc *= ((P0 >> b) & 1u) ? svb : cvb;
    }
    float cv0 = trig[0], sv0 = trig[NQ];
    float C0 = pc * ((P0 & 1u) ? sv0 : cv0);
    float C1 = pc * ((P0 & 1u) ? cv0 : -sv0);
    float cb[6], sb[6];
#pragma unroll
    for (int k = 0; k < 6; ++k) { cb[k] = trig[16 + k]; sb[k] = trig[NQ + 16 + k]; }
    unsigned u0 = P0 >> 16;                                // 6 bits
    float v0[32], v1[32];
#pragma unroll
    for (int e = 0; e < 32; ++e) {
        unsigned F = 0;
        if (e & 1)  F ^= M.frowHi[0];
        if (e & 2)  F ^= M.frowHi[1];
        if (e & 4)  F ^= M.frowHi[2];
        if (e & 8)  F ^= M.frowHi[3];
        if (e & 16) F ^= M.frowHi[4];
        unsigned u = u0 ^ (F >> 16);
        float vp = (u & 1u) ? sb[0] : cb[0];
#pragma unroll
        for (int k = 1; k < 6; ++k) vp *= ((u >> k) & 1u) ? sb[k] : cb[k];
        v0[e] = vp * C0;
        v1[e] = vp * C1;
    }
    float c2[5], s2[5];
#pragma unroll
    for (int j = 0; j < 5; ++j) {
        c2[j] = trig[2 * NQ + 17 + j];
        s2[j] = trig[3 * NQ + 17 + j];
    }
#pragma unroll
    for (int j = 0; j < 5; ++j) {
#pragma unroll
        for (int e = 0; e < 32; ++e) {
            if (!(e & (1 << j))) {
                int e1 = e | (1 << j);
                float a0 = v0[e], a1 = v0[e1];
                v0[e]  = c2[j] * a0 - s2[j] * a1;
                v0[e1] = s2[j] * a0 + c2[j] * a1;
                float b0 = v1[e], b1 = v1[e1];
                v1[e]  = c2[j] * b0 - s2[j] * b1;
                v1[e1] = s2[j] * b0 + c2[j] * b1;
            }
        }
    }
#pragma unroll
    for (int e = 0; e < 32; ++e) {
        unsigned a = base | ((unsigned)e << 17);
        phi[a] = v0[e];
        phi[DIMN + a] = v1[e];
    }
    // measure q1..q3 (x-pairs and z-masks entirely within bits 17..21)
    int lane = threadIdx.x & 63, w = threadIdx.x >> 6;
#pragma unroll
    for (int i = 1; i <= 3; ++i) {
        unsigned ex  = M.xm[i] >> 17;
        unsigned zme = M.zm[i] >> 17;
        float t00 = 0.f, t11 = 0.f, t01 = 0.f, u01 = 0.f;
#pragma unroll
        for (int e = 0; e < 32; ++e) {
            int ep = e ^ (int)ex;
            t00 += v0[e] * v0[ep];
            t11 += v1[e] * v1[ep];
            float p = v0[e] * v1[ep];
            t01 += p;
            unsigned sg = ((unsigned)__popc((unsigned)ep & zme) & 1u) << 31;
            u01 += fflip(p, sg);
        }
        float r = fold4(t00, t11, t01, u01, lane);
        if (lane < 4) red[w * 12 + (i - 1) * 4 + lane] = r;
    }
    __syncthreads();
    int t = threadIdx.x;
    if (t < 12) {
        float r = red[t] + red[12 + t] + red[24 + t] + red[36 + t];
        atomicAdd(&acc[4 + t], r);                          // acc[4..15] = q1..q3
    }
}

// ---- e=bits12..16 tile: gates 12..16 + measure q5..q8 ----
__global__ __launch_bounds__(256, 1) void k_midA(float* __restrict__ phi,
                                                 const float* __restrict__ trig,
                                                 float* __restrict__ acc) {
    constexpr MaskSet M = buildMasks();
    __shared__ float red[4 * 16];
    unsigned tid = blockIdx.x * 256u + threadIdx.x;        // [0, 2^17)
    unsigned base = (tid & 0xFFFu) | ((tid >> 12) << 17);  // bits 0..11 + 17..21
    float v0[32], v1[32];
#pragma unroll
    for (int e = 0; e < 32; ++e) {
        unsigned a = base | ((unsigned)e << 12);
        v0[e] = phi[a];
        v1[e] = phi[DIMN + a];
    }
    float c[5], s[5];
#pragma unroll
    for (int j = 0; j < 5; ++j) {
        c[j] = trig[2 * NQ + 12 + j];
        s[j] = trig[3 * NQ + 12 + j];
    }
#pragma unroll
    for (int j = 0; j < 5; ++j) {
#pragma unroll
        for (int e = 0; e < 32; ++e) {
            if (!(e & (1 << j))) {
                int e1 = e | (1 << j);
                float a0 = v0[e], a1 = v0[e1];
                v0[e]  = c[j] * a0 - s[j] * a1;
                v0[e1] = s[j] * a0 + c[j] * a1;
                float b0 = v1[e], b1 = v1[e1];
                v1[e]  = c[j] * b0 - s[j] * b1;
                v1[e1] = s[j] * b0 + c[j] * b1;
            }
        }
    }
#pragma unroll
    for (int e = 0; e < 32; ++e) {
        unsigned a = base | ((unsigned)e << 12);
        phi[a] = v0[e];
        phi[DIMN + a] = v1[e];
    }
    // measure q5..q8 (x-pairs within bits 12..16; z-masks suffix >= 13)
    int lane = threadIdx.x & 63, w = threadIdx.x >> 6;
#pragma unroll
    for (int i = 5; i <= 8; ++i) {
        unsigned ex  = (M.xm[i] >> 12) & 31u;
        unsigned zme = (M.zm[i] >> 12) & 31u;
        unsigned bs31 = ((unsigned)__popc(base & M.zm[i]) & 1u) << 31;
        float t00 = 0.f, t11 = 0.f, t01 = 0.f, u01 = 0.f;
#pragma unroll
        for (int e = 0; e < 32; ++e) {
            int ep = e ^ (int)ex;
            t00 += v0[e] * v0[ep];
            t11 += v1[e] * v1[ep];
            float p = v0[e] * v1[ep];
            t01 += p;
            unsigned sg = ((unsigned)__popc((unsigned)ep & zme) & 1u) << 31;
            u01 += fflip(p, sg ^ bs31);
        }
        float r = fold4(t00, t11, t01, u01, lane);
        if (lane < 4) red[w * 16 + (i - 5) * 4 + lane] = r;
    }
    __syncthreads();
    int t = threadIdx.x;
    if (t < 16) {
        float r = red[t] + red[16 + t] + red[32 + t] + red[48 + t];
        atomicAdd(&acc[20 + t], r);                         // acc[20..35] = q5..q8
    }
}

// ---- RY layer 2 bits 0..11 + q10..q20 X/Y + ALL Z measurements ----
__global__ __launch_bounds__(256) void k_low(float* __restrict__ phi,
                                             const float* __restrict__ trig,
                                             float* __restrict__ acc) {
    constexpr MaskSet M = buildMasks();
    __shared__ float As[4096];
    __shared__ float Bs[4096];
    __shared__ float red[4 * 44];
    float4* As4 = (float4*)As;
    float4* Bs4 = (float4*)Bs;
    int t = threadIdx.x;
    unsigned base = blockIdx.x * 4096u;
    float a[16], b[16];

    // ---- phase 0: global load (16 consecutive elems/thread), gates bits 0..3 ----
    {
        const float4* g0 = (const float4*)(phi + base);
        const float4* g1 = (const float4*)(phi + DIMN + base);
#pragma unroll
        for (int k = 0; k < 4; ++k) {
            float4 va = g0[4 * t + k];
            a[4 * k] = va.x; a[4 * k + 1] = va.y; a[4 * k + 2] = va.z; a[4 * k + 3] = va.w;
            float4 vb = g1[4 * t + k];
            b[4 * k] = vb.x; b[4 * k + 1] = vb.y; b[4 * k + 2] = vb.z; b[4 * k + 3] = vb.w;
        }
#pragma unroll
        for (int g = 0; g < 4; ++g) {
            float c = trig[2 * NQ + g], s = trig[3 * NQ + g];
#pragma unroll
            for (int e = 0; e < 16; ++e) {
                if (!(e & (1 << g))) {
                    int e1 = e | (1 << g);
                    float x0 = a[e], x1 = a[e1];
                    a[e] = c * x0 - s * x1; a[e1] = s * x0 + c * x1;
                    float y0 = b[e], y1 = b[e1];
                    b[e] = c * y0 - s * y1; b[e1] = s * y0 + c * y1;
                }
            }
        }
        unsigned sw = (unsigned)(t >> 4) & 3u;
#pragma unroll
        for (int k = 0; k < 4; ++k) {
            unsigned f = ((unsigned)(4 * t + k)) ^ sw;
            As4[f] = make_float4(a[4 * k], a[4 * k + 1], a[4 * k + 2], a[4 * k + 3]);
            Bs4[f] = make_float4(b[4 * k], b[4 * k + 1], b[4 * k + 2], b[4 * k + 3]);
        }
    }
    __syncthreads();

    // ---- phase 1: exchange to bits 4..7 ownership, gates bits 4..7 ----
    {
        unsigned lo = (unsigned)t & 15u, hi = (unsigned)t >> 4;
        unsigned swz = (hi & 3u) << 2;
#pragma unroll
        for (int j = 0; j < 16; ++j) {
            unsigned i = lo | ((unsigned)j << 4) | (hi << 8);
            a[j] = As[i ^ swz];
            b[j] = Bs[i ^ swz];
        }
#pragma unroll
        for (int g = 0; g < 4; ++g) {
            float c = trig[2 * NQ + 4 + g], s = trig[3 * NQ + 4 + g];
#pragma unroll
            for (int e = 0; e < 16; ++e) {
                if (!(e & (1 << g))) {
                    int e1 = e | (1 << g);
                    float x0 = a[e], x1 = a[e1];
                    a[e] = c * x0 - s * x1; a[e1] = s * x0 + c * x1;
                    float y0 = b[e], y1 = b[e1];
                    b[e] = c * y0 - s * y1; b[e1] = s * y0 + c * y1;
                }
            }
        }
#pragma unroll
        for (int j = 0; j < 16; ++j) {
            unsigned i = lo | ((unsigned)j << 4) | (hi << 8);
            As[i ^ swz] = a[j];
            Bs[i ^ swz] = b[j];
        }
    }
    __syncthreads();

    // ---- phase 2: exchange to bits 8..11 ownership, gates bits 8..11, write out ----
    {
#pragma unroll
        for (int j = 0; j < 16; ++j) {
            unsigned i = (unsigned)t | ((unsigned)j << 8);
            unsigned p = i ^ (((unsigned)j & 3u) << 2);
            a[j] = As[p];
            b[j] = Bs[p];
        }
#pragma unroll
        for (int g = 0; g < 4; ++g) {
            float c = trig[2 * NQ + 8 + g], s = trig[3 * NQ + 8 + g];
#pragma unroll
            for (int e = 0; e < 16; ++e) {
                if (!(e & (1 << g))) {
                    int e1 = e | (1 << g);
                    float x0 = a[e], x1 = a[e1];
                    a[e] = c * x0 - s * x1; a[e1] = s * x0 + c * x1;
                    float y0 = b[e], y1 = b[e1];
                    b[e] = c * y0 - s * y1; b[e1] = s * y0 + c * y1;
                }
            }
        }
#pragma unroll
        for (int j = 0; j < 16; ++j) {
            unsigned i = (unsigned)t | ((unsigned)j << 8);
            phi[base + i] = a[j];
            phi[DIMN + base + i] = b[j];
            unsigned p = i ^ (((unsigned)j & 3u) << 2);
            As[p] = a[j];
            Bs[p] = b[j];
        }
    }

    // ---- fused Z measurement from final registers a[],b[] ----
    float SSv[3], z0v[3], z1v[3], z2v[3], d4v[3];
    {
#pragma unroll
        for (int c = 0; c < 3; ++c) {
            float p[16];
#pragma unroll
            for (int j = 0; j < 16; ++j)
                p[j] = (c == 0) ? a[j] * a[j] : (c == 1) ? b[j] * b[j] : a[j] * b[j];
            float s1[8], d1[8];
#pragma unroll
            for (int j = 0; j < 8; ++j) { s1[j] = p[j] + p[j + 8]; d1[j] = p[j] - p[j + 8]; }
            float s2[4], d2[4];
#pragma unroll
            for (int j = 0; j < 4; ++j) { s2[j] = s1[j] + s1[j + 4]; d2[j] = d1[j] - d1[j + 4]; }
            float d3a = d2[0] - d2[2], d3b = d2[1] - d2[3];
            SSv[c] = (s2[0] + s2[1]) + (s2[2] + s2[3]);
            z0v[c] = ((d1[0] + d1[1]) + (d1[2] + d1[3])) + ((d1[4] + d1[5]) + (d1[6] + d1[7]));
            z1v[c] = (d2[0] + d2[1]) + (d2[2] + d2[3]);
            z2v[c] = d3a + d3b;
            d4v[c] = d3a - d3b;
        }
    }
    int lane = t & 63, w = t >> 6;
    // ---- cross-thread Z reductions: fold4 for {SS,z0,z1,z2}, Walsh butterfly for d4 ----
    // Quantity for qubit q needs sign parity(t-bits >= m); lane bits 0..5 handled by the
    // 6-stage Hadamard butterfly (lane L holds sum with sign (-1)^popc(L&lane); suffix
    // masks L = 0,32,48,56,60,62,63 have popc = 0..6); wave bits 6..7 applied at combine.
#pragma unroll
    for (int c = 0; c < 3; ++c) {
        float r = fold4(SSv[c], z0v[c], z1v[c], z2v[c], lane);
        if (lane < 4) red[w * 33 + c * 11 + lane] = r;
        float v = d4v[c];
#pragma unroll
        for (int s2 = 0; s2 < 6; ++s2) {
            float u = __shfl_xor(v, 1 << s2);
            v = u + fflip(v, ((unsigned)(lane >> s2) & 1u) << 31);
        }
        int pcnt = __popc(lane);
        if (lane == 64 - (64 >> pcnt)) red[w * 33 + c * 11 + 4 + pcnt] = v;
    }
    __syncthreads();
    if (t < 66) {
        int c = t % 3, q = t / 3;
        int idx, wm;
        if (q == 0 || q == 21)      { idx = 10;    wm = 3; }  // m=0: full suffix
        else if (q <= 9)            { idx = 0;     wm = 0; }  // SS (suffix cut above tile)
        else if (q <= 13)           { idx = q - 9; wm = 0; }  // q10..13 -> z0,z1,z2,d4-plain
        else if (q == 14)           { idx = 4;     wm = 2; }  // m=7: wave bit 1 only
        else if (q == 15)           { idx = 4;     wm = 3; }  // m=6: both wave bits
        else                        { idx = q - 11; wm = 3; } // q16..20 -> m=5..1
        float val = 0.f;
#pragma unroll
        for (int ww = 0; ww < 4; ++ww) {
            float rv = red[ww * 33 + c * 11 + idx];
            val += ((__popc(ww & wm) & 1) ? -rv : rv);
        }
        unsigned sg = (unsigned)__popc(base & M.zm[q]) & 1u;
        atomicAdd(&acc[4 * NQ + 3 * q + c], sg ? -val : val);
    }
    __syncthreads();

    // ---- q10..q12 measured from registers (x-pairs within bits 8..11 = j bits) ----
#pragma unroll
    for (int i = 0; i < 3; ++i) {
        constexpr int qn0 = 10;
        unsigned je  = (M.xm[qn0 + i] >> 8) & 15u;
        unsigned zmj = (M.zm[qn0 + i] >> 8) & 15u;
        unsigned zb31 = ((unsigned)__popc(base & M.zm[qn0 + i]) & 1u) << 31;
        float t00 = 0.f, t11 = 0.f, t01 = 0.f, u01 = 0.f;
#pragma unroll
        for (int j = 0; j < 16; ++j) {
            int jp = j ^ (int)je;
            t00 += a[j] * a[jp];
            t11 += b[j] * b[jp];
            float p = a[j] * b[jp];
            t01 += p;
            unsigned sg = ((unsigned)__popc((unsigned)jp & zmj) & 1u) << 31;
            u01 += fflip(p, sg ^ zb31);
        }
        float r = fold4(t00, t11, t01, u01, lane);
        if (lane < 4) red[w * 44 + 4 * i + lane] = r;
    }

    // ---- q13..q20 (masks within bits 0..8), vectorized from LDS ----
#pragma unroll
    for (int i = 3; i < 11; ++i) {
        unsigned m = M.xm[10 + i], zm = M.zm[10 + i];
        unsigned zb = (unsigned)__popc(base & zm) & 1u;
        float t00 = 0.f, t11 = 0.f, t01 = 0.f, u01 = 0.f;
        if (i < 10) {
            int gb = topbit_c(M.xm[10 + i]) - 2;
            unsigned mg4 = m >> 2;
            unsigned swap2 = m & 3u;            // 0 or 2
#pragma unroll
            for (int r = 0; r < 2; ++r) {
                unsigned gc = (unsigned)t + 256u * r;
                unsigned g = ((gc >> gb) << (gb + 1)) | (gc & ((1u << gb) - 1u));
                unsigned gx = g ^ mg4;
                float4 a0 = As4[ph4(g)],  a1 = Bs4[ph4(g)];
                float4 b0 = As4[ph4(gx)], b1 = Bs4[ph4(gx)];
                if (swap2) {
                    b0 = make_float4(b0.z, b0.w, b0.x, b0.y);
                    b1 = make_float4(b1.z, b1.w, b1.x, b1.y);
                }
                unsigned szg = ((unsigned)__popc((g << 2) & zm) + zb) & 1u;
                unsigned szx = ((unsigned)__popc((gx << 2) & zm) + zb) & 1u;
                unsigned fg = szg << 31, fx = szx << 31;
                const float* A0 = &a0.x; const float* A1 = &a1.x;
                const float* B0 = &b0.x; const float* B1 = &b1.x;
#pragma unroll
                for (int j = 0; j < 4; ++j) {
                    t00 += A0[j] * B0[j];
                    t11 += A1[j] * B1[j];
                    float p = A0[j] * B1[j], r2 = B0[j] * A1[j];
                    t01 += p + r2;
                    u01 += fflip(p, fx) + fflip(r2, fg);
                }
            }
            t00 *= 2.f; t11 *= 2.f;
        } else {
            // q20: m = 3, partner within float4
#pragma unroll
            for (int k = 0; k < 4; ++k) {
                unsigned g = (unsigned)t + 256u * k;
                float4 a0 = As4[ph4(g)], a1 = Bs4[ph4(g)];
                unsigned szg = ((unsigned)__popc((g << 2) & zm) + zb) & 1u;
                const float* A0 = &a0.x; const float* A1 = &a1.x;
#pragma unroll
                for (int j = 0; j < 4; ++j) {
                    int jx = j ^ 3;
                    float p = A0[j] * A0[jx];
                    float q2 = A1[j] * A1[jx];
                    float cr = A0[j] * A1[jx];
                    t00 += p; t11 += q2; t01 += cr;
                    unsigned sj = ((unsigned)(jx >> 1) & 1u) ^ szg;   // zm&3 == 2
                    u01 += fflip(cr, sj << 31);
                }
            }
        }
        float r = fold4(t00, t11, t01, u01, lane);
        if (lane < 4) red[w * 44 + 4 * i + lane] = r;
    }
    __syncthreads();
    if (t < 44) {
        float r = red[t] + red[44 + t] + red[88 + t] + red[132 + t];
        atomicAdd(&acc[40 + t], r);
    }
}

// ------- fused single-pass X/Y measurements for q0, q4, q9, q21 --------------
__global__ __launch_bounds__(256) void k_measF(const float* __restrict__ phi,
                                               float* __restrict__ acc) {
    constexpr MaskSet M = buildMasks();
    constexpr unsigned GA = orbGen(0), GB = orbGen(1), GC = orbGen(2);
    constexpr int pc0 = topbit_c(GC), pc1 = topbit_c(GB), pc2 = topbit_c(GA);
    __shared__ float red[4 * 16];
    unsigned t = blockIdx.x * 256u + threadIdx.x;          // 17-bit orbit id
    unsigned g = t;                                        // insert 0 at canonical bits
    g = ((g >> pc0) << (pc0 + 1)) | (g & ((1u << pc0) - 1u));
    g = ((g >> pc1) << (pc1 + 1)) | (g & ((1u << pc1) - 1u));
    g = ((g >> pc2) << (pc2 + 1)) | (g & ((1u << pc2) - 1u));
    const float4* P0 = (const float4*)phi;
    const float4* P1 = (const float4*)(phi + DIMN);
    unsigned idx[8];
    float4 u4[8], w4[8];
#pragma unroll
    for (int s = 0; s < 8; ++s) {
        idx[s] = g ^ ((s & 1) ? GA : 0u) ^ ((s & 2) ? GB : 0u) ^ ((s & 4) ? GC : 0u);
        u4[s] = P0[idx[s]];
        w4[s] = P1[idx[s]];
    }
    constexpr int QN[4] = { 0, 4, 9, 21 };
    constexpr int SX[4] = { 1, 2, 4, orbS21() };
    float res[16];
#pragma unroll
    for (int qi = 0; qi < 4; ++qi) {
        const unsigned xq = M.xm[QN[qi]];
        const unsigned zq = M.zm[QN[qi]];
        const int sx = SX[qi];
        const int mu = (int)(xq & 3u);                     // within-f4 partner xor
        const unsigned zh = zq >> 2, zl = zq & 3u;
        unsigned fz[8];
#pragma unroll
        for (int s = 0; s < 8; ++s)
            fz[s] = ((unsigned)__popc(idx[s] & zh) & 1u) << 31;
        unsigned pj31[4];
#pragma unroll
        for (int j = 0; j < 4; ++j)
            pj31[j] = ((unsigned)__popc((unsigned)j & zl) & 1u) << 31;
        float t00 = 0.f, t11 = 0.f, t01 = 0.f, u01 = 0.f;
#pragma unroll
        for (int s = 0; s < 8; ++s) {
            const int s2 = s ^ sx;
            const float* A0 = &u4[s].x;
            const float* A1 = &w4[s].x;
            const float* B0 = &u4[s2].x;
            const float* B1 = &w4[s2].x;
            const unsigned fe = fz[s2];                    // Z-parity of partner f4
#pragma unroll
            for (int j = 0; j < 4; ++j) {
                const int jp = j ^ mu;
                t00 += A0[j] * B0[jp];
                t11 += A1[j] * B1[jp];
                float p = A0[j] * B1[jp];
                t01 += p;
                u01 += fflip(p, fe ^ pj31[jp]);
            }
        }
        res[4 * qi + 0] = t00; res[4 * qi + 1] = t11;
        res[4 * qi + 2] = t01; res[4 * qi + 3] = u01;
    }
    int lane = threadIdx.x & 63, w = threadIdx.x >> 6;
#pragma unroll
    for (int g4 = 0; g4 < 4; ++g4) {
        float r = fold4(res[4 * g4 + 0], res[4 * g4 + 1], res[4 * g4 + 2], res[4 * g4 + 3], lane);
        if (lane < 4) red[w * 16 + 4 * g4 + lane] = r;
    }
    __syncthreads();
    int tt = threadIdx.x;
    if (tt < 16) {
        int qi = tt >> 2;
        int base4 = (qi == 0) ? 0 : (qi == 1) ? 16 : (qi == 2) ? 36 : 84;  // 4*qn
        float r = red[tt] + red[16 + tt] + red[32 + tt] + red[48 + tt];
        atomicAdd(&acc[base4 + (tt & 3)], r);
    }
}

// ---------------- finalize: combine 154 sums into the scalar loss ----------------
__global__ __launch_bounds__(64) void k_final(const float* __restrict__ acc,
                                              float* __restrict__ out) {
    int t = threadIdx.x;
    float v = 0.f;
    if (t < NQ) {
        float t00 = acc[4 * t], t11 = acc[4 * t + 1];
        float t01 = acc[4 * t + 2], u01 = acc[4 * t + 3];
        float d = t00 - t11;
        v = 0.5f * d * d + 2.f * t01 * t01 + 2.f * u01 * u01;   // X op + Y op
    } else if (t < 2 * NQ) {
        int q = t - NQ;
        float z0 = acc[4 * NQ + 3 * q], z1 = acc[4 * NQ + 3 * q + 1];
        float zz = acc[4 * NQ + 3 * q + 2];
        float d = z0 - z1;
        v = 0.5f * d * d + 2.f * zz * zz;                       // Z op
    }
    v += __shfl_down(v, 32); v += __shfl_down(v, 16); v += __shfl_down(v, 8);
    v += __shfl_down(v, 4);  v += __shfl_down(v, 2);  v += __shfl_down(v, 1);
    if (t == 0) out[0] = v;
}

extern "C" void kernel_launch(void* const* d_in, const int* in_sizes, int n_in,
                              void* d_out, int out_size, void* d_ws, size_t ws_size,
                              hipStream_t stream) {
    const float* theta = (const float*)d_in[0];
    float* out  = (float*)d_out;
    float* ws   = (float*)d_ws;
    float* phi  = ws;                          // 2 * DIMN floats (32 MB)
    float* acc  = ws + 2 * (size_t)DIMN;       // 256 floats
    float* trig = acc + 256;                   // 88 floats

    k_prep<<<1, 256, 0, stream>>>(theta, acc, trig);
    k_genHi<<<512, 256, 0, stream>>>(phi, trig, acc);
    k_midA<<<512, 256, 0, stream>>>(phi, trig, acc);
    k_low<<<1024, 256, 0, stream>>>(phi, trig, acc);
    k_measF<<<512, 256, 0, stream>>>(phi, acc);
    k_final<<<1, 64, 0, stream>>>(acc, out);
}

// Round 3
// 156.336 us; speedup vs baseline: 1.0818x; 1.0088x over previous
//
#include <hip/hip_runtime.h>

#define NQ 22
#define DIMN (1u << NQ)

// ---------------- compile-time circuit algebra (circuit is fixed) ----------------
struct MaskSet {
    unsigned L[NQ];      // CNOT-ring layer over GF(2): bit b of Lx = parity(x & L[b])
    unsigned Linv[NQ];
    unsigned xm[NQ];     // conjugated X masks
    unsigned zm[NQ];     // conjugated Z masks (suffix masks)
    unsigned frowHi[5];  // P-toggle masks for y bits 17..21 (columns of Linv)
};

constexpr MaskSet buildMasks() {
    MaskSet M{};
    for (int b = 0; b < NQ; ++b) M.L[b] = 1u << b;
    for (int q = 0; q < NQ; ++q) {
        int bc = NQ - 1 - q, bt = NQ - 1 - ((q + 1) % NQ);
        M.L[bt] ^= M.L[bc];
    }
    unsigned mat[NQ] = {}, aug[NQ] = {};
    for (int b = 0; b < NQ; ++b) { mat[b] = M.L[b]; aug[b] = 1u << b; }
    for (int col = 0; col < NQ; ++col) {
        int piv = col;
        while (!((mat[piv] >> col) & 1u)) ++piv;
        unsigned tm = mat[piv]; mat[piv] = mat[col]; mat[col] = tm;
        unsigned ta = aug[piv]; aug[piv] = aug[col]; aug[col] = ta;
        for (int r = 0; r < NQ; ++r)
            if (r != col && ((mat[r] >> col) & 1u)) { mat[r] ^= mat[col]; aug[r] ^= aug[col]; }
    }
    for (int b = 0; b < NQ; ++b) M.Linv[b] = aug[b];
    for (int j = 0; j < NQ; ++j) {
        int b = NQ - 1 - j;
        unsigned xmv = 0;
        for (int r = 0; r < NQ; ++r)
            if ((aug[r] >> b) & 1u) xmv |= 1u << r;
        M.xm[j] = xmv;       // q0..9: {21-j,20-j}; q10..20: low pairs; q21: {0,20,21}
        M.zm[j] = M.L[b];    // suffix masks
    }
    for (int j = 0; j < 5; ++j) {
        unsigned f = 0;
        for (int r = 0; r < NQ; ++r)
            if ((aug[r] >> (17 + j)) & 1u) f |= 1u << r;
        M.frowHi[j] = f;
    }
    return M;
}
constexpr int topbit_c(unsigned v) { int b = 0; while (v >> (b + 1)) ++b; return b; }
constexpr unsigned unionHi() {
    MaskSet M = buildMasks();
    unsigned u = 0;
    for (int j = 0; j < 5; ++j) u |= M.frowHi[j];
    return u;
}
static_assert((unionHi() & 0xFFFFu) == 0, "frowHi must only touch bits 16..21");

// ---- orbit structure for the fused slice-measurement kernel (q0,q4,q9,q21) ----
constexpr unsigned orbGen(int which) {
    MaskSet M = buildMasks();
    return (which == 0 ? M.xm[0] : which == 1 ? M.xm[4] : M.xm[9]) >> 2;
}
constexpr int orbS21() {
    MaskSet M = buildMasks();
    unsigned GA = M.xm[0] >> 2, GB = M.xm[4] >> 2, GC = M.xm[9] >> 2;
    unsigned GQ = M.xm[21] >> 2;
    for (int s = 1; s < 8; ++s) {
        unsigned c = ((s & 1) ? GA : 0u) ^ ((s & 2) ? GB : 0u) ^ ((s & 4) ? GC : 0u);
        if (c == GQ) return s;
    }
    return -1;
}
constexpr bool orbitOK() {
    unsigned GA = orbGen(0), GB = orbGen(1), GC = orbGen(2);
    int cA = topbit_c(GA), cB = topbit_c(GB), cC = topbit_c(GC);
    if (!(cC < cB && cB < cA) || cA > 19) return false;
    if (((GA >> cB) & 1u) || ((GA >> cC) & 1u)) return false;
    if (((GB >> cA) & 1u) || ((GB >> cC) & 1u)) return false;
    if (((GC >> cA) & 1u) || ((GC >> cB) & 1u)) return false;
    return orbS21() > 0;
}
static_assert(orbitOK(), "orbit structure for fused slice measurement must hold");

// sanity for the new k_low bit plan: q10,q11 X-pairs inside bits 9..11; q12..q19
// generic (m&3==0, zm&3==0); q20 special (m==3, zm&3==2)
constexpr bool lowPlanOK() {
    MaskSet M = buildMasks();
    if ((M.xm[10] & ~0xE00u) != 0) return false;
    if ((M.xm[11] & ~0xE00u) != 0) return false;
    for (int q = 12; q <= 19; ++q) {
        if ((M.xm[q] & 3u) != 0 && (M.xm[q] & 3u) != 2u) return false;
        if ((M.zm[q] & 3u) != 0) return false;
        if (topbit_c(M.xm[q]) < 2 || topbit_c(M.xm[q]) > 9) return false;
    }
    if (M.xm[20] != 3u) return false;
    if ((M.zm[20] & 3u) != 2u) return false;
    return true;
}
static_assert(lowPlanOK(), "k_low measurement plan must hold");

__device__ __forceinline__ float fflip(float v, unsigned sbit31) {
    return __int_as_float(__float_as_int(v) ^ (int)sbit31);
}
__device__ __forceinline__ unsigned ph4(unsigned g) { return g ^ ((g >> 6) & 3u); }

// element-addressed LDS bank map for the k_low exchange phases.
// A(i) = i ^ ((i>>3)&7) ^ (((i>>6)&3)<<3): bank bits = (i0^i3, i1^i4, i2^i5, i3^i6, i4^i7)
// -> full-rank on every phase's lane-entropy subspace => <=2 lanes/bank (free).
__device__ __forceinline__ unsigned sA(unsigned i) {
    return i ^ ((i >> 3) & 7u) ^ (((i >> 6) & 3u) << 3);
}

// 4-quantity wave reduction: 7 shfl instead of 24.
// Returns: lane L holds the full-wave total of quantity (L&3).
__device__ __forceinline__ float fold4(float a, float b, float c, float d, int lane) {
    bool p0 = (lane & 1) != 0;
    float kL = p0 ? b : a, sL = p0 ? a : b;
    kL += __shfl_xor(sL, 1);
    float kH = p0 ? d : c, sH = p0 ? c : d;
    kH += __shfl_xor(sH, 1);
    bool p1 = (lane & 2) != 0;
    float k2 = p1 ? kH : kL, s2 = p1 ? kL : kH;
    k2 += __shfl_xor(s2, 2);
    k2 += __shfl_xor(k2, 4);
    k2 += __shfl_xor(k2, 8);
    k2 += __shfl_xor(k2, 16);
    k2 += __shfl_xor(k2, 32);
    return k2;
}

// 3 RY gates on local element bits 0..2 (global bits b0..b0+2) for both states
__device__ __forceinline__ void gates3(float* a, float* b, const float* __restrict__ trig, int b0) {
#pragma unroll
    for (int g = 0; g < 3; ++g) {
        float c = trig[2 * NQ + b0 + g], s = trig[3 * NQ + b0 + g];
#pragma unroll
        for (int e = 0; e < 8; ++e) {
            if (!(e & (1 << g))) {
                int e1 = e | (1 << g);
                float x0 = a[e], x1 = a[e1];
                a[e] = c * x0 - s * x1; a[e1] = s * x0 + c * x1;
                float y0 = b[e], y1 = b[e1];
                b[e] = c * y0 - s * y1; b[e1] = s * y0 + c * y1;
            }
        }
    }
}

// ---------------- prep: zero accumulators, compute cos/sin tables ----------------
__global__ __launch_bounds__(256) void k_prep(const float* __restrict__ theta,
                                              float* __restrict__ acc,
                                              float* __restrict__ trig) {
    int t = threadIdx.x;
    acc[t] = 0.f;
    if (t < 2 * NQ) {
        int l = t / NQ, q = t % NQ, b = NQ - 1 - q;
        float h = 0.5f * theta[t];
        trig[l * 2 * NQ + b]      = cosf(h);
        trig[l * 2 * NQ + NQ + b] = sinf(h);
    }
}

// ---- generator in e=bits17..21 tile + gates 17..21 + measure q1,q2,q3 ----
__global__ __launch_bounds__(256, 1) void k_genHi(float* __restrict__ phi,
                                                  const float* __restrict__ trig,
                                                  float* __restrict__ acc) {
    constexpr MaskSet M = buildMasks();
    __shared__ float red[4 * 12];
    unsigned base = blockIdx.x * 256u + threadIdx.x;       // y bits 0..16
    unsigned P0 = 0;
#pragma unroll
    for (int b = 0; b < NQ; ++b)
        P0 |= ((unsigned)__popc(base & M.Linv[b]) & 1u) << b;
    float pc = 1.f;
#pragma unroll
    for (int b = 1; b < 16; ++b) {
        float cvb = trig[b], svb = trig[NQ + b];
        pc *= ((P0 >> b) & 1u) ? svb : cvb;
    }
    float cv0 = trig[0], sv0 = trig[NQ];
    float C0 = pc * ((P0 & 1u) ? sv0 : cv0);
    float C1 = pc * ((P0 & 1u) ? cv0 : -sv0);
    float cb[6], sb[6];
#pragma unroll
    for (int k = 0; k < 6; ++k) { cb[k] = trig[16 + k]; sb[k] = trig[NQ + 16 + k]; }
    unsigned u0 = P0 >> 16;                                // 6 bits
    float v0[32], v1[32];
#pragma unroll
    for (int e = 0; e < 32; ++e) {
        unsigned F = 0;
        if (e & 1)  F ^= M.frowHi[0];
        if (e & 2)  F ^= M.frowHi[1];
        if (e & 4)  F ^= M.frowHi[2];
        if (e & 8)  F ^= M.frowHi[3];
        if (e & 16) F ^= M.frowHi[4];
        unsigned u = u0 ^ (F >> 16);
        float vp = (u & 1u) ? sb[0] : cb[0];
#pragma unroll
        for (int k = 1; k < 6; ++k) vp *= ((u >> k) & 1u) ? sb[k] : cb[k];
        v0[e] = vp * C0;
        v1[e] = vp * C1;
    }
    float c2[5], s2[5];
#pragma unroll
    for (int j = 0; j < 5; ++j) {
        c2[j] = trig[2 * NQ + 17 + j];
        s2[j] = trig[3 * NQ + 17 + j];
    }
#pragma unroll
    for (int j = 0; j < 5; ++j) {
#pragma unroll
        for (int e = 0; e < 32; ++e) {
            if (!(e & (1 << j))) {
                int e1 = e | (1 << j);
                float a0 = v0[e], a1 = v0[e1];
                v0[e]  = c2[j] * a0 - s2[j] * a1;
                v0[e1] = s2[j] * a0 + c2[j] * a1;
                float b0 = v1[e], b1 = v1[e1];
                v1[e]  = c2[j] * b0 - s2[j] * b1;
                v1[e1] = s2[j] * b0 + c2[j] * b1;
            }
        }
    }
#pragma unroll
    for (int e = 0; e < 32; ++e) {
        unsigned a = base | ((unsigned)e << 17);
        phi[a] = v0[e];
        phi[DIMN + a] = v1[e];
    }
    // measure q1..q3 (x-pairs and z-masks entirely within bits 17..21)
    int lane = threadIdx.x & 63, w = threadIdx.x >> 6;
#pragma unroll
    for (int i = 1; i <= 3; ++i) {
        unsigned ex  = M.xm[i] >> 17;
        unsigned zme = M.zm[i] >> 17;
        float t00 = 0.f, t11 = 0.f, t01 = 0.f, u01 = 0.f;
#pragma unroll
        for (int e = 0; e < 32; ++e) {
            int ep = e ^ (int)ex;
            t00 += v0[e] * v0[ep];
            t11 += v1[e] * v1[ep];
            float p = v0[e] * v1[ep];
            t01 += p;
            unsigned sg = ((unsigned)__popc((unsigned)ep & zme) & 1u) << 31;
            u01 += fflip(p, sg);
        }
        float r = fold4(t00, t11, t01, u01, lane);
        if (lane < 4) red[w * 12 + (i - 1) * 4 + lane] = r;
    }
    __syncthreads();
    int t = threadIdx.x;
    if (t < 12) {
        float r = red[t] + red[12 + t] + red[24 + t] + red[36 + t];
        atomicAdd(&acc[4 + t], r);                          // acc[4..15] = q1..q3
    }
}

// ---- e=bits12..16 tile: gates 12..16 + measure q5..q8 ----
__global__ __launch_bounds__(256, 1) void k_midA(float* __restrict__ phi,
                                                 const float* __restrict__ trig,
                                                 float* __restrict__ acc) {
    constexpr MaskSet M = buildMasks();
    __shared__ float red[4 * 16];
    unsigned tid = blockIdx.x * 256u + threadIdx.x;        // [0, 2^17)
    unsigned base = (tid & 0xFFFu) | ((tid >> 12) << 17);  // bits 0..11 + 17..21
    float v0[32], v1[32];
#pragma unroll
    for (int e = 0; e < 32; ++e) {
        unsigned a = base | ((unsigned)e << 12);
        v0[e] = phi[a];
        v1[e] = phi[DIMN + a];
    }
    float c[5], s[5];
#pragma unroll
    for (int j = 0; j < 5; ++j) {
        c[j] = trig[2 * NQ + 12 + j];
        s[j] = trig[3 * NQ + 12 + j];
    }
#pragma unroll
    for (int j = 0; j < 5; ++j) {
#pragma unroll
        for (int e = 0; e < 32; ++e) {
            if (!(e & (1 << j))) {
                int e1 = e | (1 << j);
                float a0 = v0[e], a1 = v0[e1];
                v0[e]  = c[j] * a0 - s[j] * a1;
                v0[e1] = s[j] * a0 + c[j] * a1;
                float b0 = v1[e], b1 = v1[e1];
                v1[e]  = c[j] * b0 - s[j] * b1;
                v1[e1] = s[j] * b0 + c[j] * b1;
            }
        }
    }
#pragma unroll
    for (int e = 0; e < 32; ++e) {
        unsigned a = base | ((unsigned)e << 12);
        phi[a] = v0[e];
        phi[DIMN + a] = v1[e];
    }
    // measure q5..q8 (x-pairs within bits 12..16; z-masks suffix >= 13)
    int lane = threadIdx.x & 63, w = threadIdx.x >> 6;
#pragma unroll
    for (int i = 5; i <= 8; ++i) {
        unsigned ex  = (M.xm[i] >> 12) & 31u;
        unsigned zme = (M.zm[i] >> 12) & 31u;
        unsigned bs31 = ((unsigned)__popc(base & M.zm[i]) & 1u) << 31;
        float t00 = 0.f, t11 = 0.f, t01 = 0.f, u01 = 0.f;
#pragma unroll
        for (int e = 0; e < 32; ++e) {
            int ep = e ^ (int)ex;
            t00 += v0[e] * v0[ep];
            t11 += v1[e] * v1[ep];
            float p = v0[e] * v1[ep];
            t01 += p;
            unsigned sg = ((unsigned)__popc((unsigned)ep & zme) & 1u) << 31;
            u01 += fflip(p, sg ^ bs31);
        }
        float r = fold4(t00, t11, t01, u01, lane);
        if (lane < 4) red[w * 16 + (i - 5) * 4 + lane] = r;
    }
    __syncthreads();
    int t = threadIdx.x;
    if (t < 16) {
        float r = red[t] + red[16 + t] + red[32 + t] + red[48 + t];
        atomicAdd(&acc[20 + t], r);                         // acc[20..35] = q5..q8
    }
}

// ---- RY layer 2 bits 0..11 + q10..q20 X/Y + ALL Z measurements ----
// 512 threads, 8 elems/thread, 4 exchange phases -> 32 waves/CU (LDS 35 KB, 4 blk/CU)
__global__ __launch_bounds__(512, 8) void k_low(float* __restrict__ phi,
                                                const float* __restrict__ trig,
                                                float* __restrict__ acc) {
    constexpr MaskSet M = buildMasks();
    __shared__ float As[4096];
    __shared__ float Bs[4096];
    __shared__ float redZ[8 * 33];
    __shared__ float redQ[8 * 44];
    float4* As4 = (float4*)As;
    float4* Bs4 = (float4*)Bs;
    int t = threadIdx.x;
    int lane = t & 63, w = t >> 6;
    unsigned base = blockIdx.x * 4096u;
    float a[8], b[8];

    // ---- P0: load (8 consecutive elems/thread), gates bits 0..2, store ----
    {
        const float4* g0 = (const float4*)(phi + base);
        const float4* g1 = (const float4*)(phi + DIMN + base);
#pragma unroll
        for (int k = 0; k < 2; ++k) {
            float4 va = g0[2 * t + k];
            a[4 * k] = va.x; a[4 * k + 1] = va.y; a[4 * k + 2] = va.z; a[4 * k + 3] = va.w;
            float4 vb = g1[2 * t + k];
            b[4 * k] = vb.x; b[4 * k + 1] = vb.y; b[4 * k + 2] = vb.z; b[4 * k + 3] = vb.w;
        }
        gates3(a, b, trig, 0);
#pragma unroll
        for (int j = 0; j < 8; ++j) {
            unsigned i = ((unsigned)t << 3) | (unsigned)j;
            unsigned A = sA(i);
            As[A] = a[j]; Bs[A] = b[j];
        }
    }
    __syncthreads();

    // ---- X01 read (j = bits 3..5), gates 3..5, write back same addresses ----
    {
#pragma unroll
        for (int j = 0; j < 8; ++j) {
            unsigned i = (((unsigned)t >> 3) << 6) | ((unsigned)j << 3) | ((unsigned)t & 7u);
            unsigned A = sA(i);
            a[j] = As[A]; b[j] = Bs[A];
        }
        gates3(a, b, trig, 3);
#pragma unroll
        for (int j = 0; j < 8; ++j) {
            unsigned i = (((unsigned)t >> 3) << 6) | ((unsigned)j << 3) | ((unsigned)t & 7u);
            unsigned A = sA(i);
            As[A] = a[j]; Bs[A] = b[j];
        }
    }
    __syncthreads();

    // ---- X12 read (j = bits 6..8), gates 6..8, write back ----
    {
#pragma unroll
        for (int j = 0; j < 8; ++j) {
            unsigned i = (((unsigned)t >> 6) << 9) | ((unsigned)j << 6) | ((unsigned)t & 63u);
            unsigned A = sA(i);
            a[j] = As[A]; b[j] = Bs[A];
        }
        gates3(a, b, trig, 6);
#pragma unroll
        for (int j = 0; j < 8; ++j) {
            unsigned i = (((unsigned)t >> 6) << 9) | ((unsigned)j << 6) | ((unsigned)t & 63u);
            unsigned A = sA(i);
            As[A] = a[j]; Bs[A] = b[j];
        }
    }
    __syncthreads();

    // ---- X23 read (j = bits 9..11), gates 9..11 ----
    {
#pragma unroll
        for (int j = 0; j < 8; ++j) {
            unsigned i = ((unsigned)j << 9) | (unsigned)t;
            unsigned A = sA(i);
            a[j] = As[A]; b[j] = Bs[A];
        }
        gates3(a, b, trig, 9);
    }
    __syncthreads();   // protect As/Bs before measurement-layout overwrite

    // ---- write phi + measurement-layout LDS (elem i at i ^ (((i>>8)&3)<<2)) ----
#pragma unroll
    for (int j = 0; j < 8; ++j) {
        unsigned i = ((unsigned)j << 9) | (unsigned)t;
        phi[base + i] = a[j];
        phi[DIMN + base + i] = b[j];
        unsigned p = i ^ (((i >> 8) & 3u) << 2);
        As[p] = a[j]; Bs[p] = b[j];
    }

    // ---- fused Z measurement from regs: 3-level tree (bits 9..11) + lane Walsh ----
#pragma unroll
    for (int c = 0; c < 3; ++c) {
        float p[8];
#pragma unroll
        for (int j = 0; j < 8; ++j)
            p[j] = (c == 0) ? a[j] * a[j] : (c == 1) ? b[j] * b[j] : a[j] * b[j];
        float s1[4], d1[4];
#pragma unroll
        for (int j = 0; j < 4; ++j) { s1[j] = p[j] + p[j + 4]; d1[j] = p[j] - p[j + 4]; }
        float s2_0 = s1[0] + s1[2], s2_1 = s1[1] + s1[3];
        float d2_0 = d1[0] - d1[2], d2_1 = d1[1] - d1[3];
        float SS = s2_0 + s2_1;
        float z0 = (d1[0] + d1[1]) + (d1[2] + d1[3]);     // sign: bit 11
        float z1 = d2_0 + d2_1;                           // sign: bits 11,10
        float d3 = d2_0 - d2_1;                           // sign: bits 11,10,9
        float r = fold4(SS, z0, z1, 0.f, lane);
        if (lane < 3) redZ[w * 33 + c * 11 + lane] = r;
        float v = d3;
#pragma unroll
        for (int s = 0; s < 6; ++s) {
            float u = __shfl_xor(v, 1 << s);
            v = u + fflip(v, ((unsigned)(lane >> s) & 1u) << 31);
        }
        int pcnt = __popc(lane);
        if (lane == 64 - (64 >> pcnt)) redZ[w * 33 + c * 11 + 3 + pcnt] = v;
    }
    __syncthreads();   // redZ + measurement-layout As/Bs visible

    // ---- Z combine over 8 waves with wave-bit signs (elem bits 6..8) ----
    if (t < 66) {
        int c = t % 3, q = t / 3;
        int idx, wm;
        if (q == 0 || q == 21)      { idx = 9; wm = 7; }   // full suffix
        else if (q <= 9)            { idx = 0; wm = 0; }   // SS (suffix above tile)
        else if (q == 10)           { idx = 1; wm = 0; }
        else if (q == 11)           { idx = 2; wm = 0; }
        else if (q == 12)           { idx = 3; wm = 0; }
        else if (q == 13)           { idx = 3; wm = 4; }
        else if (q == 14)           { idx = 3; wm = 6; }
        else if (q == 15)           { idx = 3; wm = 7; }
        else                        { idx = q - 12; wm = 7; }  // q16..q20 -> 4..8
        float val = 0.f;
#pragma unroll
        for (int ww = 0; ww < 8; ++ww) {
            float rv = redZ[ww * 33 + c * 11 + idx];
            val += ((__popc(ww & wm) & 1) ? -rv : rv);
        }
        unsigned sg = (unsigned)__popc(base & M.zm[q]) & 1u;
        atomicAdd(&acc[4 * NQ + 3 * q + c], sg ? -val : val);
    }

    // ---- q10,q11 from registers (x-pairs within bits 9..11 = j bits) ----
#pragma unroll
    for (int i = 0; i < 2; ++i) {
        int q = 10 + i;
        unsigned je  = (M.xm[q] >> 9) & 7u;
        unsigned zmj = (M.zm[q] >> 9) & 7u;
        unsigned zb31 = ((unsigned)__popc(base & M.zm[q]) & 1u) << 31;
        float t00 = 0.f, t11 = 0.f, t01 = 0.f, u01 = 0.f;
#pragma unroll
        for (int j = 0; j < 8; ++j) {
            int jp = j ^ (int)je;
            t00 += a[j] * a[jp];
            t11 += b[j] * b[jp];
            float p = a[j] * b[jp];
            t01 += p;
            unsigned sg = ((unsigned)__popc((unsigned)jp & zmj) & 1u) << 31;
            u01 += fflip(p, sg ^ zb31);
        }
        float r = fold4(t00, t11, t01, u01, lane);
        if (lane < 4) redQ[w * 44 + 4 * i + lane] = r;
    }

    // ---- q12..q19 (generic float4-pair path), q20 special ----
#pragma unroll
    for (int iq = 2; iq < 10; ++iq) {
        int q = 10 + iq;
        unsigned m = M.xm[q], zm = M.zm[q];
        unsigned zb = (unsigned)__popc(base & zm) & 1u;
        int gb = topbit_c(M.xm[q]) - 2;
        unsigned mg4 = m >> 2;
        unsigned swap2 = m & 3u;            // 0 or 2
        float t00 = 0.f, t11 = 0.f, t01 = 0.f, u01 = 0.f;
        unsigned gc = (unsigned)t;          // 0..511: covers all 512 half-pairs
        unsigned g = ((gc >> gb) << (gb + 1)) | (gc & ((1u << gb) - 1u));
        unsigned gx = g ^ mg4;
        float4 a0 = As4[ph4(g)],  a1 = Bs4[ph4(g)];
        float4 b0 = As4[ph4(gx)], b1 = Bs4[ph4(gx)];
        if (swap2) {
            b0 = make_float4(b0.z, b0.w, b0.x, b0.y);
            b1 = make_float4(b1.z, b1.w, b1.x, b1.y);
        }
        unsigned szg = ((unsigned)__popc((g << 2) & zm) + zb) & 1u;
        unsigned szx = ((unsigned)__popc((gx << 2) & zm) + zb) & 1u;
        unsigned fg = szg << 31, fx = szx << 31;
        const float* A0 = &a0.x; const float* A1 = &a1.x;
        const float* B0 = &b0.x; const float* B1 = &b1.x;
#pragma unroll
        for (int j = 0; j < 4; ++j) {
            t00 += A0[j] * B0[j];
            t11 += A1[j] * B1[j];
            float p = A0[j] * B1[j], r2 = B0[j] * A1[j];
            t01 += p + r2;
            u01 += fflip(p, fx) + fflip(r2, fg);
        }
        t00 *= 2.f; t11 *= 2.f;
        float r = fold4(t00, t11, t01, u01, lane);
        if (lane < 4) redQ[w * 44 + 4 * iq + lane] = r;
    }
    {
        // q20: m = 3, partner within float4; zm&3 == 2
        unsigned zm = M.zm[20];
        unsigned zb = (unsigned)__popc(base & zm) & 1u;
        float t00 = 0.f, t11 = 0.f, t01 = 0.f, u01 = 0.f;
#pragma unroll
        for (int k = 0; k < 2; ++k) {
            unsigned g = (unsigned)t + 512u * k;
            float4 a0 = As4[ph4(g)], a1 = Bs4[ph4(g)];
            unsigned szg = ((unsigned)__popc((g << 2) & zm) + zb) & 1u;
            const float* A0 = &a0.x; const float* A1 = &a1.x;
#pragma unroll
            for (int j = 0; j < 4; ++j) {
                int jx = j ^ 3;
                float p = A0[j] * A0[jx];
                float q2 = A1[j] * A1[jx];
                float cr = A0[j] * A1[jx];
                t00 += p; t11 += q2; t01 += cr;
                unsigned sj = ((unsigned)(jx >> 1) & 1u) ^ szg;   // zm&3 == 2
                u01 += fflip(cr, sj << 31);
            }
        }
        float r = fold4(t00, t11, t01, u01, lane);
        if (lane < 4) redQ[w * 44 + 40 + lane] = r;
    }
    __syncthreads();
    if (t < 44) {
        float r = 0.f;
#pragma unroll
        for (int ww = 0; ww < 8; ++ww) r += redQ[ww * 44 + t];
        atomicAdd(&acc[40 + t], r);
    }
}

// ------- fused single-pass X/Y measurements for q0, q4, q9, q21 --------------
__global__ __launch_bounds__(256) void k_measF(const float* __restrict__ phi,
                                               float* __restrict__ acc) {
    constexpr MaskSet M = buildMasks();
    constexpr unsigned GA = orbGen(0), GB = orbGen(1), GC = orbGen(2);
    constexpr int pc0 = topbit_c(GC), pc1 = topbit_c(GB), pc2 = topbit_c(GA);
    __shared__ float red[4 * 16];
    unsigned t = blockIdx.x * 256u + threadIdx.x;          // 17-bit orbit id
    unsigned g = t;                                        // insert 0 at canonical bits
    g = ((g >> pc0) << (pc0 + 1)) | (g & ((1u << pc0) - 1u));
    g = ((g >> pc1) << (pc1 + 1)) | (g & ((1u << pc1) - 1u));
    g = ((g >> pc2) << (pc2 + 1)) | (g & ((1u << pc2) - 1u));
    const float4* P0 = (const float4*)phi;
    const float4* P1 = (const float4*)(phi + DIMN);
    unsigned idx[8];
    float4 u4[8], w4[8];
#pragma unroll
    for (int s = 0; s < 8; ++s) {
        idx[s] = g ^ ((s & 1) ? GA : 0u) ^ ((s & 2) ? GB : 0u) ^ ((s & 4) ? GC : 0u);
        u4[s] = P0[idx[s]];
        w4[s] = P1[idx[s]];
    }
    constexpr int QN[4] = { 0, 4, 9, 21 };
    constexpr int SX[4] = { 1, 2, 4, orbS21() };
    float res[16];
#pragma unroll
    for (int qi = 0; qi < 4; ++qi) {
        const unsigned xq = M.xm[QN[qi]];
        const unsigned zq = M.zm[QN[qi]];
        const int sx = SX[qi];
        const int mu = (int)(xq & 3u);                     // within-f4 partner xor
        const unsigned zh = zq >> 2, zl = zq & 3u;
        unsigned fz[8];
#pragma unroll
        for (int s = 0; s < 8; ++s)
            fz[s] = ((unsigned)__popc(idx[s] & zh) & 1u) << 31;
        unsigned pj31[4];
#pragma unroll
        for (int j = 0; j < 4; ++j)
            pj31[j] = ((unsigned)__popc((unsigned)j & zl) & 1u) << 31;
        float t00 = 0.f, t11 = 0.f, t01 = 0.f, u01 = 0.f;
#pragma unroll
        for (int s = 0; s < 8; ++s) {
            const int s2 = s ^ sx;
            const float* A0 = &u4[s].x;
            const float* A1 = &w4[s].x;
            const float* B0 = &u4[s2].x;
            const float* B1 = &w4[s2].x;
            const unsigned fe = fz[s2];                    // Z-parity of partner f4
#pragma unroll
            for (int j = 0; j < 4; ++j) {
                const int jp = j ^ mu;
                t00 += A0[j] * B0[jp];
                t11 += A1[j] * B1[jp];
                float p = A0[j] * B1[jp];
                t01 += p;
                u01 += fflip(p, fe ^ pj31[jp]);
            }
        }
        res[4 * qi + 0] = t00; res[4 * qi + 1] = t11;
        res[4 * qi + 2] = t01; res[4 * qi + 3] = u01;
    }
    int lane = threadIdx.x & 63, w = threadIdx.x >> 6;
#pragma unroll
    for (int g4 = 0; g4 < 4; ++g4) {
        float r = fold4(res[4 * g4 + 0], res[4 * g4 + 1], res[4 * g4 + 2], res[4 * g4 + 3], lane);
        if (lane < 4) red[w * 16 + 4 * g4 + lane] = r;
    }
    __syncthreads();
    int tt = threadIdx.x;
    if (tt < 16) {
        int qi = tt >> 2;
        int base4 = (qi == 0) ? 0 : (qi == 1) ? 16 : (qi == 2) ? 36 : 84;  // 4*qn
        float r = red[tt] + red[16 + tt] + red[32 + tt] + red[48 + tt];
        atomicAdd(&acc[base4 + (tt & 3)], r);
    }
}

// ---------------- finalize: combine 154 sums into the scalar loss ----------------
__global__ __launch_bounds__(64) void k_final(const float* __restrict__ acc,
                                              float* __restrict__ out) {
    int t = threadIdx.x;
    float v = 0.f;
    if (t < NQ) {
        float t00 = acc[4 * t], t11 = acc[4 * t + 1];
        float t01 = acc[4 * t + 2], u01 = acc[4 * t + 3];
        float d = t00 - t11;
        v = 0.5f * d * d + 2.f * t01 * t01 + 2.f * u01 * u01;   // X op + Y op
    } else if (t < 2 * NQ) {
        int q = t - NQ;
        float z0 = acc[4 * NQ + 3 * q], z1 = acc[4 * NQ + 3 * q + 1];
        float zz = acc[4 * NQ + 3 * q + 2];
        float d = z0 - z1;
        v = 0.5f * d * d + 2.f * zz * zz;                       // Z op
    }
    v += __shfl_down(v, 32); v += __shfl_down(v, 16); v += __shfl_down(v, 8);
    v += __shfl_down(v, 4);  v += __shfl_down(v, 2);  v += __shfl_down(v, 1);
    if (t == 0) out[0] = v;
}

extern "C" void kernel_launch(void* const* d_in, const int* in_sizes, int n_in,
                              void* d_out, int out_size, void* d_ws, size_t ws_size,
                              hipStream_t stream) {
    const float* theta = (const float*)d_in[0];
    float* out  = (float*)d_out;
    float* ws   = (float*)d_ws;
    float* phi  = ws;                          // 2 * DIMN floats (32 MB)
    float* acc  = ws + 2 * (size_t)DIMN;       // 256 floats
    float* trig = acc + 256;                   // 88 floats

    k_prep<<<1, 256, 0, stream>>>(theta, acc, trig);
    k_genHi<<<512, 256, 0, stream>>>(phi, trig, acc);
    k_midA<<<512, 256, 0, stream>>>(phi, trig, acc);
    k_low<<<1024, 512, 0, stream>>>(phi, trig, acc);
    k_measF<<<512, 256, 0, stream>>>(phi, acc);
    k_final<<<1, 64, 0, stream>>>(acc, out);
}